// Round 6
// baseline (107.866 us; speedup 1.0000x reference)
//
#include <hip/hip_runtime.h>
#include <stdint.h>
#include <stddef.h>

#define Bv 16
#define Cv 256
#define Hv 64
#define Wv 64
#define Kv 1024
#define HWv (Hv * Wv)   // 4096
#define Nv (Bv * HWv)   // 65536

typedef float f32x4 __attribute__((ext_vector_type(4)));
typedef unsigned short u16x4 __attribute__((ext_vector_type(4)));
typedef unsigned short u16x8 __attribute__((ext_vector_type(8)));
typedef __bf16 bf16x8 __attribute__((ext_vector_type(8)));

__device__ __forceinline__ unsigned short f2bf(float f) {
  unsigned u = __builtin_bit_cast(unsigned, f);
  u += 0x7fffu + ((u >> 16) & 1u);   // RNE
  return (unsigned short)(u >> 16);
}

__device__ __forceinline__ void gl_lds16(const void* g, void* l) {
  __builtin_amdgcn_global_load_lds(
      (const __attribute__((address_space(1))) unsigned int*)g,
      (__attribute__((address_space(3))) unsigned int*)l, 16, 0, 0);
}

// ---------------- Kernel 1: embedding prep -> FRAGMENT-MAJOR bf16 ---------
// ebf byte layout: (col,k) -> ct*8192 + cc*1024 + l4*256 + l15*16 + j*2
//   ct=col>>4, l15=col&15, cc=k>>5, l4=(k>>3)&3, j=k&7
// This makes the GEMM's LDS fragment read contiguous (base + lane*16):
// canonical conflict-free ds_read_b128, and staging a pure linear copy.
__global__ __launch_bounds__(64) void k_prep(const float* __restrict__ e,
                                             unsigned char* __restrict__ ebf,
                                             float* __restrict__ eq) {
  int k = blockIdx.x;          // codebook row = col, 0..1023
  int lane = threadIdx.x;      // 0..63
  const float* row = e + (size_t)k * Cv;
  f32x4 v = *(const f32x4*)(row + lane * 4);
  u16x4 bv = { f2bf(v[0]), f2bf(v[1]), f2bf(v[2]), f2bf(v[3]) };
  int ct = k >> 4, l15 = k & 15;
  int cc = lane >> 3;              // (lane*4)>>5
  int l4 = (lane >> 1) & 3;        // ((lane*4)>>3)&3
  int j8 = (lane & 1) * 8;         // byte offset of j within the 16B unit
  *(u16x4*)(ebf + (size_t)ct * 8192 + cc * 1024 + l4 * 256 + l15 * 16 + j8) = bv;
  float p = v[0]*v[0] + v[1]*v[1] + v[2]*v[2] + v[3]*v[3];
  #pragma unroll
  for (int off = 32; off > 0; off >>= 1) p += __shfl_down(p, off);
  if (lane == 0) eq[k] = p;
}

// ---------------- Kernel 2: z (NCHW) -> zp (NHWC flat [N][C]) --------------
__global__ __launch_bounds__(256) void k_transpose(const float* __restrict__ z,
                                                   float* __restrict__ zp) {
  __shared__ float t[64][65];
  int tn = blockIdx.x & 1023;
  int tc = blockIdx.x >> 10;      // 0..3
  int n0 = tn * 64;
  int b  = n0 >> 12;
  int hw0 = n0 & 4095;
  int c0 = tc * 64;
  int tid = threadIdx.x;

  int cl  = tid >> 4;             // 0..15
  int hw4 = (tid & 15) * 4;
  #pragma unroll
  for (int p = 0; p < 4; ++p) {
    int c = p * 16 + cl;
    f32x4 v = *(const f32x4*)(z + ((size_t)b * Cv + (c0 + c)) * HWv + hw0 + hw4);
    t[c][hw4 + 0] = v[0]; t[c][hw4 + 1] = v[1];
    t[c][hw4 + 2] = v[2]; t[c][hw4 + 3] = v[3];
  }
  __syncthreads();

  int nl = tid >> 2;              // 0..63
  int cb = (tid & 3) * 4;
  float* orow = zp + (size_t)(n0 + nl) * Cv + c0;
  #pragma unroll
  for (int q = 0; q < 4; ++q) {
    int c = cb + q * 16;
    f32x4 v = { t[c][nl], t[c + 1][nl], t[c + 2][nl], t[c + 3][nl] };
    *(f32x4*)(orow + c) = v;
  }
}

// ---------------- Kernel 3: GEMM + argmin + gather (fused tail) ------------
// 128 rows/block. A-frags direct from z. B streamed as 32-col (16KB) chunks,
// double-buffered, staged with global_load_lds (linear: ebf pre-swizzled).
// One {vmcnt(0); barrier} per chunk; stage issued before compute (T3 2-phase).
#define CHUNK_B 16384
#define NCHUNKS 32

__global__ __launch_bounds__(256) void k_gg(const float* __restrict__ z,
                                            const float* __restrict__ e,
                                            const unsigned char* __restrict__ ebf,
                                            const float* __restrict__ eq,
                                            float* __restrict__ zout,
                                            float* __restrict__ zq) {
  __shared__ union alignas(16) {
    float t[64][129];                    // gather transpose tile (33024 B)
    unsigned char bl[2][CHUNK_B];        // GEMM B double-buffer (32768 B)
  } sm;
  __shared__ int il[128];

  int tid  = threadIdx.x;
  int lane = tid & 63;
  int wid  = tid >> 6;            // 0..3
  int l15  = lane & 15;
  int l4   = lane >> 4;           // 0..3
  int n0   = blockIdx.x * 128;
  int b    = n0 >> 12;
  int hw0  = n0 & 4095;
  int row0 = wid * 32;            // block-local row base for this wave

  // ---- A-fragments straight from z ----
  u16x8 afr[2][8];
  #pragma unroll
  for (int rt = 0; rt < 2; ++rt) {
    const float* zr = z + (size_t)b * Cv * HWv + hw0 + row0 + rt * 16 + l15;
    #pragma unroll
    for (int cc = 0; cc < 8; ++cc) {
      int cbase = cc * 32 + l4 * 8;
      u16x8 a;
      #pragma unroll
      for (int j = 0; j < 8; ++j)
        a[j] = f2bf(zr[(size_t)(cbase + j) * HWv]);
      afr[rt][cc] = a;
    }
  }

  float minv[2][4];
  int   mini[2][4];
  #pragma unroll
  for (int rt = 0; rt < 2; ++rt)
    #pragma unroll
    for (int j = 0; j < 4; ++j) { minv[rt][j] = 3.0e38f; mini[rt][j] = 0; }

  // ---- prologue: stage chunk 0 into buf 0 ----
  {
    const unsigned char* s0 = ebf + wid * 1024 + lane * 16;
    unsigned char* d0 = sm.bl[0] + wid * 1024;
    #pragma unroll
    for (int it = 0; it < 4; ++it)
      gl_lds16(s0 + it * 4096, d0 + it * 4096);
  }
  asm volatile("s_waitcnt vmcnt(0)" ::: "memory");
  __syncthreads();

  for (int nc = 0; nc < NCHUNKS; ++nc) {
    int cur = nc & 1;
    // stage next chunk into the other buffer (latency hides under compute)
    if (nc < NCHUNKS - 1) {
      const unsigned char* s0 = ebf + (size_t)(nc + 1) * CHUNK_B + wid * 1024 + lane * 16;
      unsigned char* d0 = sm.bl[cur ^ 1] + wid * 1024;
      #pragma unroll
      for (int it = 0; it < 4; ++it)
        gl_lds16(s0 + it * 4096, d0 + it * 4096);
    }

    // compute on buf cur: 2 col-tiles x (8 conflict-free ds_read_b128 + 16 MFMA)
    #pragma unroll
    for (int ctl = 0; ctl < 2; ++ctl) {
      int col = nc * 32 + ctl * 16 + l15;
      float eqv = eq[col];
      u16x8 bfr[8];
      #pragma unroll
      for (int cc = 0; cc < 8; ++cc)
        bfr[cc] = *(const u16x8*)(sm.bl[cur] + ctl * 8192 + cc * 1024 + lane * 16);
      #pragma unroll
      for (int rt = 0; rt < 2; ++rt) {
        f32x4 acc = { 0.f, 0.f, 0.f, 0.f };
        #pragma unroll
        for (int cc = 0; cc < 8; ++cc)
          acc = __builtin_amdgcn_mfma_f32_16x16x32_bf16(
                  __builtin_bit_cast(bf16x8, afr[rt][cc]),
                  __builtin_bit_cast(bf16x8, bfr[cc]), acc, 0, 0, 0);
        #pragma unroll
        for (int j = 0; j < 4; ++j) {
          float s = fmaf(-2.0f, acc[j], eqv);
          // cols ascend -> strict '<' keeps lowest index (np.argmin semantics)
          if (s < minv[rt][j]) { minv[rt][j] = s; mini[rt][j] = col; }
        }
      }
    }

    asm volatile("s_waitcnt vmcnt(0)" ::: "memory");  // own stage loads landed
    __syncthreads();                                  // all waves' loads visible
  }

  // ---- argmin reduce across the 16 col-lanes -> il[] ----
  #pragma unroll
  for (int rt = 0; rt < 2; ++rt) {
    #pragma unroll
    for (int j = 0; j < 4; ++j) {
      float v = minv[rt][j];
      int   ix = mini[rt][j];
      #pragma unroll
      for (int off = 1; off < 16; off <<= 1) {
        float ov = __shfl_xor(v, off);
        int   oi = __shfl_xor(ix, off);
        if (ov < v || (ov == v && oi < ix)) { v = ov; ix = oi; }
      }
      if (l15 == 0) il[row0 + rt * 16 + l4 * 4 + j] = ix;
    }
  }
  __syncthreads();   // il visible; all waves done with sm.bl

  // ---- gather tail: e rows -> zq (coalesced) + zout (LDS transpose) ----
  {
    int nq  = tid >> 4;           // 0..15
    int cq  = (tid & 15) * 4;
    int c_l = tid >> 5;           // 0..7
    int hwq = tid & 31;
    #pragma unroll
    for (int cch = 0; cch < 4; ++cch) {
      int c0 = cch * 64;
      #pragma unroll
      for (int it = 0; it < 8; ++it) {
        int n = it * 16 + nq;
        f32x4 v = *(const f32x4*)(e + (size_t)il[n] * Cv + c0 + cq);
        *(f32x4*)(zq + (size_t)(n0 + n) * Cv + c0 + cq) = v;
        sm.t[cq + 0][n] = v[0]; sm.t[cq + 1][n] = v[1];
        sm.t[cq + 2][n] = v[2]; sm.t[cq + 3][n] = v[3];
      }
      __syncthreads();
      #pragma unroll
      for (int it = 0; it < 8; ++it) {
        int c = it * 8 + c_l;
        f32x4 v = { sm.t[c][hwq * 4 + 0], sm.t[c][hwq * 4 + 1],
                    sm.t[c][hwq * 4 + 2], sm.t[c][hwq * 4 + 3] };
        *(f32x4*)(zout + ((size_t)(b * Cv + c0 + c)) * HWv + hw0 + hwq * 4) = v;
      }
      __syncthreads();   // protect tile before next chunk overwrites
    }
  }
}

// ---------------------------------------------------------------------------
extern "C" void kernel_launch(void* const* d_in, const int* in_sizes, int n_in,
                              void* d_out, int out_size, void* d_ws, size_t ws_size,
                              hipStream_t stream) {
  const float* z = (const float*)d_in[0];            // [16,256,64,64]
  const float* e = (const float*)d_in[1];            // [1024,256]

  float* out0 = (float*)d_out;                       // z_out  NCHW
  float* out1 = out0 + (size_t)Nv * Cv;              // z_q    [N][C]
  float* out2 = out1 + (size_t)Nv * Cv;              // zp     [N][C]

  const size_t EBF_B = (size_t)Kv * Cv * 2;          // 524288
  const size_t EQ_B  = (size_t)Kv * 4;               // 4096
  if (ws_size < EBF_B + EQ_B) return;
  unsigned char* ebf = (unsigned char*)d_ws;
  float* eq = (float*)((char*)d_ws + EBF_B);

  k_prep<<<Kv, 64, 0, stream>>>(e, ebf, eq);
  k_gg<<<Nv / 128, 256, 0, stream>>>(z, e, ebf, eq, out0, out1);
  k_transpose<<<(Nv / 64) * (Cv / 64), 256, 0, stream>>>(z, out2);
}

// Round 7
// 92.455 us; speedup vs baseline: 1.1667x; 1.1667x over previous
//
#include <hip/hip_runtime.h>
#include <stdint.h>
#include <stddef.h>

#define Bv 16
#define Cv 256
#define Hv 64
#define Wv 64
#define Kv 1024
#define HWv (Hv * Wv)   // 4096
#define Nv (Bv * HWv)   // 65536

typedef float f32x4 __attribute__((ext_vector_type(4)));
typedef unsigned short u16x4 __attribute__((ext_vector_type(4)));
typedef unsigned short u16x8 __attribute__((ext_vector_type(8)));
typedef __bf16 bf16x8 __attribute__((ext_vector_type(8)));

__device__ __forceinline__ unsigned short f2bf(float f) {
  unsigned u = __builtin_bit_cast(unsigned, f);
  u += 0x7fffu + ((u >> 16) & 1u);   // RNE
  return (unsigned short)(u >> 16);
}

__device__ __forceinline__ void gl_lds16(const void* g, void* l) {
  __builtin_amdgcn_global_load_lds(
      (const __attribute__((address_space(1))) unsigned int*)g,
      (__attribute__((address_space(3))) unsigned int*)l, 16, 0, 0);
}

// ---------------- Kernel 1: embedding prep -> FRAGMENT-MAJOR bf16 ---------
// ebf byte layout: (col,k) -> ct*8192 + cc*1024 + l4*256 + l15*16 + j*2
//   ct=col>>4, l15=col&15, cc=k>>5, l4=(k>>3)&3, j=k&7
// GEMM B-fragment read = ds_read_b128 at base + lane*16: conflict-free;
// staging is a pure linear copy (global_load_lds-compatible).
__global__ __launch_bounds__(64) void k_prep(const float* __restrict__ e,
                                             unsigned char* __restrict__ ebf,
                                             float* __restrict__ eq) {
  int k = blockIdx.x;          // codebook row = col, 0..1023
  int lane = threadIdx.x;      // 0..63
  const float* row = e + (size_t)k * Cv;
  f32x4 v = *(const f32x4*)(row + lane * 4);
  u16x4 bv = { f2bf(v[0]), f2bf(v[1]), f2bf(v[2]), f2bf(v[3]) };
  int ct = k >> 4, l15 = k & 15;
  int cc = lane >> 3;              // (lane*4)>>5
  int l4 = (lane >> 1) & 3;        // ((lane*4)>>3)&3
  int j8 = (lane & 1) * 8;         // byte offset of j within the 16B unit
  *(u16x4*)(ebf + (size_t)ct * 8192 + cc * 1024 + l4 * 256 + l15 * 16 + j8) = bv;
  float p = v[0]*v[0] + v[1]*v[1] + v[2]*v[2] + v[3]*v[3];
  #pragma unroll
  for (int off = 32; off > 0; off >>= 1) p += __shfl_down(p, off);
  if (lane == 0) eq[k] = p;
}

// ---------------- Kernel 2: z (NCHW) -> zp (NHWC flat [N][C]) --------------
// Runs BEFORE k_gg: zp is both output 2 and the GEMM's A matrix.
__global__ __launch_bounds__(256) void k_transpose(const float* __restrict__ z,
                                                   float* __restrict__ zp) {
  __shared__ float t[64][65];
  int tn = blockIdx.x & 1023;
  int tc = blockIdx.x >> 10;      // 0..3
  int n0 = tn * 64;
  int b  = n0 >> 12;
  int hw0 = n0 & 4095;
  int c0 = tc * 64;
  int tid = threadIdx.x;

  int cl  = tid >> 4;             // 0..15
  int hw4 = (tid & 15) * 4;
  #pragma unroll
  for (int p = 0; p < 4; ++p) {
    int c = p * 16 + cl;
    f32x4 v = *(const f32x4*)(z + ((size_t)b * Cv + (c0 + c)) * HWv + hw0 + hw4);
    t[c][hw4 + 0] = v[0]; t[c][hw4 + 1] = v[1];
    t[c][hw4 + 2] = v[2]; t[c][hw4 + 3] = v[3];
  }
  __syncthreads();

  int nl = tid >> 2;              // 0..63
  int cb = (tid & 3) * 4;
  float* orow = zp + (size_t)(n0 + nl) * Cv + c0;
  #pragma unroll
  for (int q = 0; q < 4; ++q) {
    int c = cb + q * 16;
    f32x4 v = { t[c][nl], t[c + 1][nl], t[c + 2][nl], t[c + 3][nl] };
    *(f32x4*)(orow + c) = v;
  }
}

// ---------------- Kernel 3: GEMM + argmin + gather (fused tail) ------------
// 128 rows/block. A-frags from zp: per (rt,cc) each lane loads 8 consecutive
// floats (2x dwordx4); (l4,j) spans 128B contiguous per row -> full cache-line
// utilization. B streamed as 64-col (32KB) chunks, double-buffered, staged
// with global_load_lds (linear; ebf pre-swizzled fragment-major). One
// {vmcnt(0); barrier} pair per chunk.
#define CHUNK_B 32768
#define NCHUNKS 16

__global__ __launch_bounds__(256) void k_gg(const float* __restrict__ zp,
                                            const float* __restrict__ e,
                                            const unsigned char* __restrict__ ebf,
                                            const float* __restrict__ eq,
                                            float* __restrict__ zout,
                                            float* __restrict__ zq) {
  __shared__ union alignas(16) {
    float t[64][129];                    // gather transpose tile (33024 B)
    unsigned char bl[2][CHUNK_B];        // GEMM B double-buffer (65536 B)
  } sm;
  __shared__ int il[128];

  int tid  = threadIdx.x;
  int lane = tid & 63;
  int wid  = tid >> 6;            // 0..3
  int l15  = lane & 15;
  int l4   = lane >> 4;           // 0..3
  int n0   = blockIdx.x * 128;
  int b    = n0 >> 12;
  int hw0  = n0 & 4095;
  int row0 = wid * 32;            // block-local row base for this wave

  // ---- prologue stage of chunk 0 issued FIRST (hides under A-build) ----
  {
    const unsigned char* s0 = ebf + wid * 1024 + lane * 16;
    unsigned char* d0 = sm.bl[0] + wid * 1024;
    #pragma unroll
    for (int it = 0; it < 8; ++it)
      gl_lds16(s0 + it * 4096, d0 + it * 4096);
  }

  // ---- A-fragments from zp: coalesced fp32 rows ----
  u16x8 afr[2][8];
  #pragma unroll
  for (int rt = 0; rt < 2; ++rt) {
    const float* ar = zp + (size_t)(n0 + row0 + rt * 16 + l15) * Cv + l4 * 8;
    #pragma unroll
    for (int cc = 0; cc < 8; ++cc) {
      f32x4 v0 = *(const f32x4*)(ar + cc * 32);
      f32x4 v1 = *(const f32x4*)(ar + cc * 32 + 4);
      afr[rt][cc] = u16x8{ f2bf(v0[0]), f2bf(v0[1]), f2bf(v0[2]), f2bf(v0[3]),
                           f2bf(v1[0]), f2bf(v1[1]), f2bf(v1[2]), f2bf(v1[3]) };
    }
  }

  float minv[2][4];
  int   mini[2][4];
  #pragma unroll
  for (int rt = 0; rt < 2; ++rt)
    #pragma unroll
    for (int j = 0; j < 4; ++j) { minv[rt][j] = 3.0e38f; mini[rt][j] = 0; }

  asm volatile("s_waitcnt vmcnt(0)" ::: "memory");
  __syncthreads();

  for (int nc = 0; nc < NCHUNKS; ++nc) {
    int cur = nc & 1;
    // stage next chunk into the other buffer (latency hides under compute)
    if (nc < NCHUNKS - 1) {
      const unsigned char* s0 = ebf + (size_t)(nc + 1) * CHUNK_B + wid * 1024 + lane * 16;
      unsigned char* d0 = sm.bl[cur ^ 1] + wid * 1024;
      #pragma unroll
      for (int it = 0; it < 8; ++it)
        gl_lds16(s0 + it * 4096, d0 + it * 4096);
    }

    // compute on buf cur: 4 col-tiles x (8 conflict-free ds_read_b128 + 16 MFMA)
    #pragma unroll
    for (int ctl = 0; ctl < 4; ++ctl) {
      int col = nc * 64 + ctl * 16 + l15;
      float eqv = eq[col];
      u16x8 bfr[8];
      #pragma unroll
      for (int cc = 0; cc < 8; ++cc)
        bfr[cc] = *(const u16x8*)(sm.bl[cur] + ctl * 8192 + cc * 1024 + lane * 16);
      #pragma unroll
      for (int rt = 0; rt < 2; ++rt) {
        f32x4 acc = { 0.f, 0.f, 0.f, 0.f };
        #pragma unroll
        for (int cc = 0; cc < 8; ++cc)
          acc = __builtin_amdgcn_mfma_f32_16x16x32_bf16(
                  __builtin_bit_cast(bf16x8, afr[rt][cc]),
                  __builtin_bit_cast(bf16x8, bfr[cc]), acc, 0, 0, 0);
        #pragma unroll
        for (int j = 0; j < 4; ++j) {
          float s = fmaf(-2.0f, acc[j], eqv);
          // cols ascend -> strict '<' keeps lowest index (np.argmin semantics)
          if (s < minv[rt][j]) { minv[rt][j] = s; mini[rt][j] = col; }
        }
      }
    }

    asm volatile("s_waitcnt vmcnt(0)" ::: "memory");  // own stage loads landed
    __syncthreads();                                  // all waves' loads visible
  }

  // ---- argmin reduce across the 16 col-lanes -> il[] ----
  #pragma unroll
  for (int rt = 0; rt < 2; ++rt) {
    #pragma unroll
    for (int j = 0; j < 4; ++j) {
      float v = minv[rt][j];
      int   ix = mini[rt][j];
      #pragma unroll
      for (int off = 1; off < 16; off <<= 1) {
        float ov = __shfl_xor(v, off);
        int   oi = __shfl_xor(ix, off);
        if (ov < v || (ov == v && oi < ix)) { v = ov; ix = oi; }
      }
      if (l15 == 0) il[row0 + rt * 16 + l4 * 4 + j] = ix;
    }
  }
  __syncthreads();   // il visible; all waves done with sm.bl

  // ---- gather tail: e rows -> zq (coalesced) + zout (LDS transpose) ----
  {
    int nq  = tid >> 4;           // 0..15
    int cq  = (tid & 15) * 4;
    int c_l = tid >> 5;           // 0..7
    int hwq = tid & 31;
    #pragma unroll
    for (int cch = 0; cch < 4; ++cch) {
      int c0 = cch * 64;
      #pragma unroll
      for (int it = 0; it < 8; ++it) {
        int n = it * 16 + nq;
        f32x4 v = *(const f32x4*)(e + (size_t)il[n] * Cv + c0 + cq);
        *(f32x4*)(zq + (size_t)(n0 + n) * Cv + c0 + cq) = v;
        sm.t[cq + 0][n] = v[0]; sm.t[cq + 1][n] = v[1];
        sm.t[cq + 2][n] = v[2]; sm.t[cq + 3][n] = v[3];
      }
      __syncthreads();
      #pragma unroll
      for (int it = 0; it < 8; ++it) {
        int c = it * 8 + c_l;
        f32x4 v = { sm.t[c][hwq * 4 + 0], sm.t[c][hwq * 4 + 1],
                    sm.t[c][hwq * 4 + 2], sm.t[c][hwq * 4 + 3] };
        *(f32x4*)(zout + ((size_t)(b * Cv + c0 + c)) * HWv + hw0 + hwq * 4) = v;
      }
      __syncthreads();   // protect tile before next chunk overwrites
    }
  }
}

// ---------------------------------------------------------------------------
extern "C" void kernel_launch(void* const* d_in, const int* in_sizes, int n_in,
                              void* d_out, int out_size, void* d_ws, size_t ws_size,
                              hipStream_t stream) {
  const float* z = (const float*)d_in[0];            // [16,256,64,64]
  const float* e = (const float*)d_in[1];            // [1024,256]

  float* out0 = (float*)d_out;                       // z_out  NCHW
  float* out1 = out0 + (size_t)Nv * Cv;              // z_q    [N][C]
  float* out2 = out1 + (size_t)Nv * Cv;              // zp     [N][C]

  const size_t EBF_B = (size_t)Kv * Cv * 2;          // 524288
  const size_t EQ_B  = (size_t)Kv * 4;               // 4096
  if (ws_size < EBF_B + EQ_B) return;
  unsigned char* ebf = (unsigned char*)d_ws;
  float* eq = (float*)((char*)d_ws + EBF_B);

  k_prep<<<Kv, 64, 0, stream>>>(e, ebf, eq);
  k_transpose<<<(Nv / 64) * (Cv / 64), 256, 0, stream>>>(z, out2);
  k_gg<<<Nv / 128, 256, 0, stream>>>(out2, e, ebf, eq, out0, out1);
}